// Round 3
// baseline (198.653 us; speedup 1.0000x reference)
//
#include <hip/hip_runtime.h>

#define HW 65536

typedef __attribute__((ext_vector_type(8))) short short8;
typedef __attribute__((ext_vector_type(4))) float float4v;

__device__ __forceinline__ int refl(int i){ if (i < 0) i = -i; if (i > 255) i = 510 - i; return i; }
__device__ __forceinline__ float lrelu(float x){ return x > 0.f ? x : 0.01f * x; }
__device__ __forceinline__ unsigned int f2bf(float x){
  union { float f; unsigned int u; } v; v.f = x;
  unsigned int r = v.u + 0x7fff + ((v.u >> 16) & 1);
  return r >> 16;
}
// HW packed f32->bf16 (RNE) -- bit-identical to f2bf pair, 1 instruction vs ~10.
__device__ __forceinline__ unsigned int pk_bf16(float lo, float hi){
  unsigned int r;
  asm("v_cvt_pk_bf16_f32 %0, %1, %2" : "=v"(r) : "v"(lo), "v"(hi));
  return r;
}
__device__ __forceinline__ unsigned short f2h(float x){
  union { _Float16 h; unsigned short u; } v; v.h = (_Float16)x; return v.u;
}
__device__ __forceinline__ float h2f(unsigned short u){
  union { _Float16 h; unsigned short u; } v; v.u = u; return (float)v.h;
}

// ---------------- K_prep: weight convert + Toeplitz tables (blocks 0..511), muC (512) ---
#define W2OFF 13312
#define W3OFF 59904
__global__ __launch_bounds__(256) void k_prep(const float* __restrict__ w1,
    const float* __restrict__ w2, const float* __restrict__ w3,
    const float* __restrict__ bl, const float* __restrict__ br,
    const float* __restrict__ mu, unsigned short* __restrict__ wbf,
    unsigned short* __restrict__ Tt, float* __restrict__ mucp){
  __shared__ float sm[650];
  __shared__ float sq[10];
  int bid = blockIdx.x;
  int tid = threadIdx.x;
  if (bid < 512){
    int i = bid * 256 + tid;
    if (i < 84992){
      if (i < 208 * 64){
        int n = i >> 6, k = i & 63;
        float v = (n < 200 && k < 33) ? w1[n * 33 + k] : 0.f;
        wbf[i] = (unsigned short)f2bf(v);
      } else if (i < W2OFF + 208 * 224){
        int j = i - W2OFF; int n = j / 224, k = j - n * 224;
        float v = (n < 200 && k < 200) ? w2[n * 200 + k] : 0.f;
        wbf[i] = (unsigned short)f2bf(v);
      } else {
        int j = i - W3OFF; int n = j / 224, k = j - n * 224;
        float v = (n < 100 && k < 200) ? w3[n * 200 + k] : 0.f;
        wbf[i] = (unsigned short)f2bf(v);
      }
    } else {
      int e = i - 84992;                 // < 46080
      int t = e / 1536, rem = e - t * 1536;
      int m = rem / 96, k = rem - m * 96;
      int d = k - m;
      float v = 0.f;
      if (d >= 0 && d <= 64){
        if (t < 10)      v = bl[d * 10 + t];
        else if (t < 20) v = mu[d * 10 + (t - 10)];
        else             v = br[d * 10 + (t - 20)];
      }
      Tt[e] = (unsigned short)f2bf(v);
    }
  } else {
    // ---- muC = sum_m (sum_u mu[u,m])^2, same op order as reference k_final ----
    for (int e = tid; e < 650; e += 256) sm[e] = mu[e];
    __syncthreads();
    if (tid < 10){
      float s = 0.f;
      for (int u = 0; u < 65; ++u) s += sm[u * 10 + tid];
      sq[tid] = s * s;
    }
    __syncthreads();
    if (tid == 0){
      float m = 0.f;
      #pragma unroll
      for (int mm = 0; mm < 10; ++mm) m += sq[mm];
      mucp[0] = m;
    }
  }
}

// ---------------- Fused MLP + gridsample: 64-pixel tile, 3 layers, MFMA bf16 ------------
// M=64: halves per-pixel weight (L2) traffic vs 32-tile, 4 independent acc chains/wave.
// HSTR=234 (117 dwords, odd) -> bank-conflict-free-ish ds_read_b128 row stride.
#define HSTR 234
#define BUFB 29952
__global__ __launch_bounds__(256) void k_mlp(const float* __restrict__ img,
    const float* __restrict__ zern,
    const float* __restrict__ b1f, const float* __restrict__ b2f,
    const float* __restrict__ b3f, const unsigned short* __restrict__ wbf,
    float* __restrict__ tilt, unsigned short* __restrict__ coefb){
  __shared__ char smem[2 * BUFB];
  unsigned short* H1  = (unsigned short*)smem;            // 64 x HSTR
  unsigned short* H3u = (unsigned short*)smem;            // 64 x 113 (alias H1)
  unsigned short* XB  = (unsigned short*)(smem + BUFB);   // 64 x 72
  unsigned short* H2  = XB;                               // 64 x HSTR (alias XB)
  int tid = threadIdx.x;
  int pix0 = blockIdx.x * 64;
  int lane = tid & 63, wv = tid >> 6;
  int ln = lane & 15, qd = lane >> 4;

  // ---- bilinear grid sample (border, align_corners=False) for this tile ----
  if (tid < 192){
    int m = tid & 63, c = tid >> 6;
    int pix = pix0 + m;
    int x = pix & 255, y = pix >> 8;
    float px = zern[pix * 35 + 0], py = zern[pix * 35 + 1];
    float ix = ((float)x + px) * (256.f / 255.f) - 0.5f;
    float iy = ((float)y + py) * (256.f / 255.f) - 0.5f;
    ix = fminf(fmaxf(ix, 0.f), 255.f);
    iy = fminf(fmaxf(iy, 0.f), 255.f);
    float x0f = floorf(ix), y0f = floorf(iy);
    float wx = ix - x0f, wy = iy - y0f;
    int x0 = (int)x0f, y0 = (int)y0f;
    int x1 = min(x0 + 1, 255), y1 = min(y0 + 1, 255);
    const float* im = img + c * HW;
    float g00 = im[y0 * 256 + x0], g01 = im[y0 * 256 + x1];
    float g10 = im[y1 * 256 + x0], g11 = im[y1 * 256 + x1];
    float top = g00 * (1.f - wx) + g01 * wx;
    float bot = g10 * (1.f - wx) + g11 * wx;
    tilt[c * HW + pix] = top * (1.f - wy) + bot * wy;
  }

  for (int e = tid; e < 2304; e += 256) ((int*)XB)[e] = 0;          // whole XB
  for (int e = tid; e < 768; e += 256){                             // H1 K-pad 200..223
    int m = e / 12, j = e - m * 12;
    ((int*)H1)[m * 117 + 100 + j] = 0;
  }
  __syncthreads();
  for (int e = tid; e < 64 * 33; e += 256){
    int m = e / 33, k = e - m * 33;
    XB[m * 72 + k] = (unsigned short)f2bf(zern[(pix0 + m) * 35 + 2 + k]);
  }
  __syncthreads();

  // ---- layer 1 ----
  for (int nt = wv; nt < 13; nt += 4){
    int n = nt * 16 + ln;
    short8 b0 = *(const short8*)(wbf + n * 64 + qd * 8);
    short8 b1 = *(const short8*)(wbf + n * 64 + 32 + qd * 8);
    float bv = (n < 200) ? b1f[n] : 0.f;
    #pragma unroll
    for (int mt = 0; mt < 4; ++mt){
      float4v acc = {bv, bv, bv, bv};
      short8 a0 = *(const short8*)(XB + (mt * 16 + ln) * 72 + qd * 8);
      short8 a1 = *(const short8*)(XB + (mt * 16 + ln) * 72 + 32 + qd * 8);
      acc = __builtin_amdgcn_mfma_f32_16x16x32_bf16(a0, b0, acc, 0, 0, 0);
      acc = __builtin_amdgcn_mfma_f32_16x16x32_bf16(a1, b1, acc, 0, 0, 0);
      #pragma unroll
      for (int r = 0; r < 4; ++r)
        H1[(mt * 16 + qd * 4 + r) * HSTR + n] = (unsigned short)f2bf(lrelu(acc[r]));
    }
  }
  __syncthreads();

  // ---- layer 2 ----
  for (int e = tid; e < 768; e += 256){                             // H2 K-pad (writes 0;
    int m = e / 12, j = e - m * 12;                                 // races with layer-2's
    ((int*)H2)[m * 117 + 100 + j] = 0;                              // zero stores -- benign)
  }
  {
    const unsigned short* w2p = wbf + W2OFF;
    for (int nt = wv; nt < 13; nt += 4){
      int n = nt * 16 + ln;
      short8 bf[7];
      #pragma unroll
      for (int kc = 0; kc < 7; ++kc)
        bf[kc] = *(const short8*)(w2p + n * 224 + kc * 32 + qd * 8);
      float bv = (n < 200) ? b2f[n] : 0.f;
      #pragma unroll
      for (int mt = 0; mt < 4; ++mt){
        float4v acc = {bv, bv, bv, bv};
        #pragma unroll
        for (int kc = 0; kc < 7; ++kc){
          short8 af = *(const short8*)(H1 + (mt * 16 + ln) * HSTR + kc * 32 + qd * 8);
          acc = __builtin_amdgcn_mfma_f32_16x16x32_bf16(af, bf[kc], acc, 0, 0, 0);
        }
        #pragma unroll
        for (int r = 0; r < 4; ++r)
          H2[(mt * 16 + qd * 4 + r) * HSTR + n] = (unsigned short)f2bf(lrelu(acc[r]));
      }
    }
  }
  __syncthreads();

  // ---- layer 3 (store f16) ----
  {
    const unsigned short* w3p = wbf + W3OFF;
    for (int nt = wv; nt < 7; nt += 4){
      int n = nt * 16 + ln;
      short8 bf[7];
      #pragma unroll
      for (int kc = 0; kc < 7; ++kc)
        bf[kc] = *(const short8*)(w3p + n * 224 + kc * 32 + qd * 8);
      float bv = (n < 100) ? b3f[n] : 0.f;
      #pragma unroll
      for (int mt = 0; mt < 4; ++mt){
        float4v acc = {bv, bv, bv, bv};
        #pragma unroll
        for (int kc = 0; kc < 7; ++kc){
          short8 af = *(const short8*)(H2 + (mt * 16 + ln) * HSTR + kc * 32 + qd * 8);
          acc = __builtin_amdgcn_mfma_f32_16x16x32_bf16(af, bf[kc], acc, 0, 0, 0);
        }
        #pragma unroll
        for (int r = 0; r < 4; ++r)
          H3u[(mt * 16 + qd * 4 + r) * 113 + n] = f2h(acc[r]);
      }
    }
  }
  __syncthreads();

  // paired u32 stores: 2 pixels per store
  for (int e = tid; e < 3200; e += 256){
    int n = e >> 5, mp = e & 31;
    unsigned int lo = H3u[(2 * mp) * 113 + n];
    unsigned int hi = H3u[(2 * mp + 1) * 113 + n];
    *(unsigned int*)(coefb + n * HW + pix0 + 2 * mp) = lo | (hi << 16);
  }
}

// ---------------- K3 v16: banded-Toeplitz MFMA vconv, f16 input, cvt_pk pack ------------
#define VB 344
__global__ __launch_bounds__(256) void k_vconv16(const float* __restrict__ tilt,
    const unsigned short* __restrict__ coefb, const unsigned short* __restrict__ Tt,
    unsigned short* __restrict__ sbuf, unsigned short* __restrict__ smu){
  __shared__ __align__(16) unsigned short sxb[2][16 * VB];
  int tid = threadIdx.x;
  int bid = blockIdx.x;
  int lane = tid & 63, wv = tid >> 6;
  int ln = lane & 15, qd = lane >> 4;
  int col = tid & 15, seg = tid >> 4;
  int r0 = seg * 20;

  int goff[20];
  #pragma unroll
  for (int q = 0; q < 20; ++q) goff[q] = refl(r0 + q - 32) * 256 + col;

  for (int e = tid; e < 768; e += 256){
    int b = e / 384, r = e - b * 384;
    int cc = r / 24, rp = r - cc * 24;
    sxb[b][cc * VB + 320 + rp] = 0;
  }

  if (bid < 640){
    int s = bid & 15;
    int cj = bid >> 4;
    int c = cj / 10, j = cj - c * 10;
    int x0 = s * 16;
    float treg[20];
    if (c < 3){
      const float* tc = tilt + c * HW + x0;
      #pragma unroll
      for (int q = 0; q < 20; ++q) treg[q] = tc[goff[q]];
    }
    unsigned short pf[20];
    {
      const unsigned short* cq = coefb + j * HW + x0;
      #pragma unroll
      for (int q = 0; q < 20; ++q) pf[q] = cq[goff[q]];
    }
    float4v acc[4];
    #pragma unroll
    for (int t = 0; t < 4; ++t) acc[t] = (float4v){0.f, 0.f, 0.f, 0.f};
    for (int i = 0; i < 10; ++i){
      int us = i & 1;
      unsigned short* sb = sxb[us];
      if (c < 3){
        #pragma unroll
        for (int q = 0; q < 10; ++q){
          float v0 = h2f(pf[2 * q]) * treg[2 * q];
          float v1 = h2f(pf[2 * q + 1]) * treg[2 * q + 1];
          *(unsigned int*)&sb[col * VB + r0 + 2 * q] = pk_bf16(v0, v1);
        }
      } else {
        #pragma unroll
        for (int q = 0; q < 10; ++q){
          *(unsigned int*)&sb[col * VB + r0 + 2 * q] = pk_bf16(h2f(pf[2 * q]), h2f(pf[2 * q + 1]));
        }
      }
      __syncthreads();
      if (i < 9){
        const unsigned short* cn = coefb + ((i + 1) * 10 + j) * HW + x0;
        #pragma unroll
        for (int q = 0; q < 20; ++q) pf[q] = cn[goff[q]];
      }
      const unsigned short* ta = Tt + i * 1536 + ln * 96 + qd * 8;
      short8 A0 = *(const short8*)(ta);
      short8 A1 = *(const short8*)(ta + 32);
      short8 A2 = *(const short8*)(ta + 64);
      #pragma unroll
      for (int t = 0; t < 4; ++t){
        int yt = wv * 4 + t;
        const unsigned short* bp = sb + ln * VB + yt * 16 + qd * 8;
        short8 B0 = *(const short8*)(bp);
        short8 B1 = *(const short8*)(bp + 32);
        short8 B2 = *(const short8*)(bp + 64);
        acc[t] = __builtin_amdgcn_mfma_f32_16x16x32_bf16(A0, B0, acc[t], 0, 0, 0);
        acc[t] = __builtin_amdgcn_mfma_f32_16x16x32_bf16(A1, B1, acc[t], 0, 0, 0);
        acc[t] = __builtin_amdgcn_mfma_f32_16x16x32_bf16(A2, B2, acc[t], 0, 0, 0);
      }
    }
    unsigned short* S = sbuf + (c * 10 + j) * HW + x0 + ln;
    #pragma unroll
    for (int t = 0; t < 4; ++t){
      int yt = wv * 4 + t;
      #pragma unroll
      for (int r = 0; r < 4; ++r)
        S[(yt * 16 + qd * 4 + r) * 256] = (unsigned short)f2bf(acc[t][r]);
    }
  } else {
    int b2 = bid - 640;
    int c = b2 >> 4, s = b2 & 15;
    int x0 = s * 16;
    const float* tc = tilt + c * HW + x0;
    float tv[20];
    #pragma unroll
    for (int q = 0; q < 20; ++q) tv[q] = tc[goff[q]];
    #pragma unroll
    for (int q = 0; q < 10; ++q){
      *(unsigned int*)&sxb[0][col * VB + r0 + 2 * q] = pk_bf16(tv[2 * q], tv[2 * q + 1]);
    }
    __syncthreads();
    for (int m = 0; m < 10; ++m){
      const unsigned short* ta = Tt + (10 + m) * 1536 + ln * 96 + qd * 8;
      short8 A0 = *(const short8*)(ta);
      short8 A1 = *(const short8*)(ta + 32);
      short8 A2 = *(const short8*)(ta + 64);
      float4v acc[4];
      #pragma unroll
      for (int t = 0; t < 4; ++t) acc[t] = (float4v){0.f, 0.f, 0.f, 0.f};
      #pragma unroll
      for (int t = 0; t < 4; ++t){
        int yt = wv * 4 + t;
        const unsigned short* bp = sxb[0] + ln * VB + yt * 16 + qd * 8;
        short8 B0 = *(const short8*)(bp);
        short8 B1 = *(const short8*)(bp + 32);
        short8 B2 = *(const short8*)(bp + 64);
        acc[t] = __builtin_amdgcn_mfma_f32_16x16x32_bf16(A0, B0, acc[t], 0, 0, 0);
        acc[t] = __builtin_amdgcn_mfma_f32_16x16x32_bf16(A1, B1, acc[t], 0, 0, 0);
        acc[t] = __builtin_amdgcn_mfma_f32_16x16x32_bf16(A2, B2, acc[t], 0, 0, 0);
      }
      unsigned short* S = smu + (c * 10 + m) * HW + x0 + ln;
      #pragma unroll
      for (int t = 0; t < 4; ++t){
        int yt = wv * 4 + t;
        #pragma unroll
        for (int r = 0; r < 4; ++r)
          S[(yt * 16 + qd * 4 + r) * 256] = (unsigned short)f2bf(acc[t][r]);
      }
    }
  }
}

// ---------------- K4 v9: Toeplitz-MFMA hconv, bf16 INPUT (no f2bf in pack) --------------
#define HS2 344
__global__ __launch_bounds__(256) void k_hconv9(const unsigned short* __restrict__ sbuf,
    const unsigned short* __restrict__ smu, const unsigned short* __restrict__ Tt,
    float* __restrict__ part){
  __shared__ __align__(16) unsigned short sxb[16 * HS2];
  int tid = threadIdx.x;
  int grp = blockIdx.x >> 4;
  int yt  = blockIdx.x & 15;
  int y0 = yt * 16;
  int lane = tid & 63, wv = tid >> 6;
  int ln = lane & 15, qd = lane >> 4;
  int srow = tid >> 4, scol = tid & 15;
  int isbr = (grp < 8);
  int tgt, h;
  if (isbr){ tgt = grp >> 1; h = grp & 1; }
  else     { int g2 = grp - 8; tgt = g2 >> 1; h = g2 & 1; }
  const unsigned short* base = isbr ? (sbuf + tgt * 10 * HW) : (smu + tgt * 10 * HW);
  int tbase = isbr ? 20 : 10;

  for (int e = tid; e < 384; e += 256){
    int rr = e / 24, cp = e - rr * 24;
    sxb[rr * HS2 + 320 + cp] = 0;
  }

  int gx[20];
  #pragma unroll
  for (int q = 0; q < 20; ++q) gx[q] = refl(scol * 20 - 32 + q);

  float4v acc[4];
  #pragma unroll
  for (int t = 0; t < 4; ++t) acc[t] = (float4v){0.f, 0.f, 0.f, 0.f};

  for (int p = 0; p < 5; ++p){
    int col = h * 5 + p;
    const unsigned short* plane = base + col * HW + (y0 + srow) * 256;
    __syncthreads();
    unsigned short v[20];
    #pragma unroll
    for (int q = 0; q < 20; ++q) v[q] = plane[gx[q]];
    #pragma unroll
    for (int q = 0; q < 10; ++q){
      *(unsigned int*)&sxb[srow * HS2 + scol * 20 + 2 * q] =
          (unsigned int)v[2 * q] | ((unsigned int)v[2 * q + 1] << 16);
    }
    __syncthreads();
    const unsigned short* ta = Tt + (tbase + col) * 1536 + ln * 96 + qd * 8;
    short8 A0 = *(const short8*)(ta);
    short8 A1 = *(const short8*)(ta + 32);
    short8 A2 = *(const short8*)(ta + 64);
    #pragma unroll
    for (int t = 0; t < 4; ++t){
      int wt = wv * 4 + t;
      const unsigned short* bp = sxb + ln * HS2 + wt * 16 + qd * 8;
      short8 B0 = *(const short8*)(bp);
      short8 B1 = *(const short8*)(bp + 32);
      short8 B2 = *(const short8*)(bp + 64);
      acc[t] = __builtin_amdgcn_mfma_f32_16x16x32_bf16(A0, B0, acc[t], 0, 0, 0);
      acc[t] = __builtin_amdgcn_mfma_f32_16x16x32_bf16(A1, B1, acc[t], 0, 0, 0);
      acc[t] = __builtin_amdgcn_mfma_f32_16x16x32_bf16(A2, B2, acc[t], 0, 0, 0);
    }
  }
  #pragma unroll
  for (int t = 0; t < 4; ++t){
    int wt = wv * 4 + t;
    float4 res = {acc[t][0], acc[t][1], acc[t][2], acc[t][3]};
    *(float4*)(part + grp * HW + (y0 + ln) * 256 + wt * 16 + qd * 4) = res;
  }
}

// ---------------- K5: out_c = (P2c+P2c+1+P8+2c+P9+2c) / (P6+P7+muC) ---------------------
__global__ __launch_bounds__(256) void k_final(const float* __restrict__ part,
                                               const float* __restrict__ mucp,
                                               float* __restrict__ out){
  int pix = blockIdx.x * 256 + threadIdx.x;
  float muC = mucp[0];
  float den = part[6 * HW + pix] + part[7 * HW + pix] + muC;
  float inv = 1.f / den;
  #pragma unroll
  for (int c = 0; c < 3; ++c){
    float num = part[(2 * c) * HW + pix] + part[(2 * c + 1) * HW + pix]
              + part[(8 + 2 * c) * HW + pix] + part[(9 + 2 * c) * HW + pix];
    out[c * HW + pix] = num * inv;
  }
}

extern "C" void kernel_launch(void* const* d_in, const int* in_sizes, int n_in,
                              void* d_out, int out_size, void* d_ws, size_t ws_size,
                              hipStream_t stream) {
  const float* img  = (const float*)d_in[0];
  const float* zern = (const float*)d_in[1];
  const float* w1   = (const float*)d_in[2];
  const float* b1   = (const float*)d_in[3];
  const float* w2   = (const float*)d_in[4];
  const float* b2   = (const float*)d_in[5];
  const float* w3   = (const float*)d_in[6];
  const float* b3   = (const float*)d_in[7];
  const float* bl   = (const float*)d_in[8];
  const float* br   = (const float*)d_in[9];
  const float* mu   = (const float*)d_in[10];
  float* out = (float*)d_out;

  float* w = (float*)d_ws;
  float* tilt = w;                                        // planes [0,3)
  unsigned short* coefb = (unsigned short*)(w + 3 * HW);  // 100 f16 planes = [3,53); dead after vconv
  float* part = w + 3 * HW;                               // planes [3,17): hconv partials (reuse coefb)
  unsigned short* sbuf = (unsigned short*)(w + 53 * HW);  // 40 bf16 planes [53,73)
  unsigned short* smu  = (unsigned short*)(w + 73 * HW);  // 30 bf16 planes [73,88)
  unsigned short* wbf  = (unsigned short*)(w + 53 * HW);  // bf16 weights, dead before vconv writes sbuf
  unsigned short* Tt   = (unsigned short*)(w + 88 * HW);  // Toeplitz tables, 90 KB
  float* mucp = (float*)(Tt + 46080);                     // 1 float

  k_prep<<<513, 256, 0, stream>>>(w1, w2, w3, bl, br, mu, wbf, Tt, mucp);
  k_mlp<<<1024, 256, 0, stream>>>(img, zern, b1, b2, b3, wbf, tilt, coefb);
  k_vconv16<<<688, 256, 0, stream>>>(tilt, coefb, Tt, sbuf, smu);
  k_hconv9<<<224, 256, 0, stream>>>(sbuf, smu, Tt, part);
  k_final<<<256, 256, 0, stream>>>(part, mucp, out);
}

// Round 4
// 193.804 us; speedup vs baseline: 1.0250x; 1.0250x over previous
//
#include <hip/hip_runtime.h>

#define HW 65536

typedef __attribute__((ext_vector_type(8))) short short8;
typedef __attribute__((ext_vector_type(4))) float float4v;

__device__ __forceinline__ int refl(int i){ if (i < 0) i = -i; if (i > 255) i = 510 - i; return i; }
__device__ __forceinline__ float lrelu(float x){ return x > 0.f ? x : 0.01f * x; }
__device__ __forceinline__ unsigned int f2bf(float x){
  union { float f; unsigned int u; } v; v.f = x;
  unsigned int r = v.u + 0x7fff + ((v.u >> 16) & 1);
  return r >> 16;
}
// HW packed f32->bf16 (RNE) -- bit-identical to f2bf pair, 1 instruction vs ~10.
__device__ __forceinline__ unsigned int pk_bf16(float lo, float hi){
  unsigned int r;
  asm("v_cvt_pk_bf16_f32 %0, %1, %2" : "=v"(r) : "v"(lo), "v"(hi));
  return r;
}
__device__ __forceinline__ unsigned short f2h(float x){
  union { _Float16 h; unsigned short u; } v; v.h = (_Float16)x; return v.u;
}
__device__ __forceinline__ float h2f(unsigned short u){
  union { _Float16 h; unsigned short u; } v; v.u = u; return (float)v.h;
}

// ---------------- K_prep: weight convert + Toeplitz tables (blocks 0..511), muC (512) ---
#define W2OFF 13312
#define W3OFF 59904
__global__ __launch_bounds__(256) void k_prep(const float* __restrict__ w1,
    const float* __restrict__ w2, const float* __restrict__ w3,
    const float* __restrict__ bl, const float* __restrict__ br,
    const float* __restrict__ mu, unsigned short* __restrict__ wbf,
    unsigned short* __restrict__ Tt, float* __restrict__ mucp){
  __shared__ float sm[650];
  __shared__ float sq[10];
  int bid = blockIdx.x;
  int tid = threadIdx.x;
  if (bid < 512){
    int i = bid * 256 + tid;
    if (i < 84992){
      if (i < 208 * 64){
        int n = i >> 6, k = i & 63;
        float v = (n < 200 && k < 33) ? w1[n * 33 + k] : 0.f;
        wbf[i] = (unsigned short)f2bf(v);
      } else if (i < W2OFF + 208 * 224){
        int j = i - W2OFF; int n = j / 224, k = j - n * 224;
        float v = (n < 200 && k < 200) ? w2[n * 200 + k] : 0.f;
        wbf[i] = (unsigned short)f2bf(v);
      } else {
        int j = i - W3OFF; int n = j / 224, k = j - n * 224;
        float v = (n < 100 && k < 200) ? w3[n * 200 + k] : 0.f;
        wbf[i] = (unsigned short)f2bf(v);
      }
    } else {
      int e = i - 84992;                 // < 46080
      int t = e / 1536, rem = e - t * 1536;
      int m = rem / 96, k = rem - m * 96;
      int d = k - m;
      float v = 0.f;
      if (d >= 0 && d <= 64){
        if (t < 10)      v = bl[d * 10 + t];
        else if (t < 20) v = mu[d * 10 + (t - 10)];
        else             v = br[d * 10 + (t - 20)];
      }
      Tt[e] = (unsigned short)f2bf(v);
    }
  } else {
    // ---- muC = sum_m (sum_u mu[u,m])^2, same op order as reference k_final ----
    for (int e = tid; e < 650; e += 256) sm[e] = mu[e];
    __syncthreads();
    if (tid < 10){
      float s = 0.f;
      for (int u = 0; u < 65; ++u) s += sm[u * 10 + tid];
      sq[tid] = s * s;
    }
    __syncthreads();
    if (tid == 0){
      float m = 0.f;
      #pragma unroll
      for (int mm = 0; mm < 10; ++mm) m += sq[mm];
      mucp[0] = m;
    }
  }
}

// ---------------- Fused MLP + gridsample: 32-pixel tile (proven TLP sweet spot) ---------
// HSTR=234 (117 dwords): R3 showed 4x fewer LDS bank conflicts per unit work vs 232.
// 2048 blocks, 29.95KB LDS -> 5 blocks/CU resident (the R3 64-tile variant halved that
// and regressed 2x -- this kernel is latency-bound, inter-block TLP is the hiding).
#define HSTR 234
#define BUFB 14976
__global__ __launch_bounds__(256) void k_mlp(const float* __restrict__ img,
    const float* __restrict__ zern,
    const float* __restrict__ b1f, const float* __restrict__ b2f,
    const float* __restrict__ b3f, const unsigned short* __restrict__ wbf,
    float* __restrict__ tilt, unsigned short* __restrict__ coefb){
  __shared__ char smem[2 * BUFB];
  unsigned short* H1  = (unsigned short*)smem;            // 32 x HSTR
  unsigned short* H3u = (unsigned short*)smem;            // 32 x 113 f16 (alias H1)
  unsigned short* XB  = (unsigned short*)(smem + BUFB);   // 32 x 72
  unsigned short* H2  = XB;                               // 32 x HSTR (alias XB)
  int tid = threadIdx.x;
  int pix0 = blockIdx.x * 32;
  int lane = tid & 63, wv = tid >> 6;
  int ln = lane & 15, qd = lane >> 4;

  // ---- bilinear grid sample (border, align_corners=False) for this tile ----
  if (tid < 96){
    int m = tid & 31, c = tid >> 5;
    int pix = pix0 + m;
    int x = pix & 255, y = pix >> 8;
    float px = zern[pix * 35 + 0], py = zern[pix * 35 + 1];
    float ix = ((float)x + px) * (256.f / 255.f) - 0.5f;
    float iy = ((float)y + py) * (256.f / 255.f) - 0.5f;
    ix = fminf(fmaxf(ix, 0.f), 255.f);
    iy = fminf(fmaxf(iy, 0.f), 255.f);
    float x0f = floorf(ix), y0f = floorf(iy);
    float wx = ix - x0f, wy = iy - y0f;
    int x0 = (int)x0f, y0 = (int)y0f;
    int x1 = min(x0 + 1, 255), y1 = min(y0 + 1, 255);
    const float* im = img + c * HW;
    float g00 = im[y0 * 256 + x0], g01 = im[y0 * 256 + x1];
    float g10 = im[y1 * 256 + x0], g11 = im[y1 * 256 + x1];
    float top = g00 * (1.f - wx) + g01 * wx;
    float bot = g10 * (1.f - wx) + g11 * wx;
    tilt[c * HW + pix] = top * (1.f - wy) + bot * wy;
  }

  for (int e = tid; e < 1152; e += 256) ((int*)XB)[e] = 0;          // whole XB
  for (int e = tid; e < 384; e += 256){                             // H1 pad shorts 208..223
    int m = e / 12, j = e - m * 12;
    ((int*)H1)[m * 117 + 104 + j] = 0;
  }
  __syncthreads();
  for (int e = tid; e < 32 * 33; e += 256){
    int m = e / 33, k = e - m * 33;
    XB[m * 72 + k] = (unsigned short)f2bf(zern[(pix0 + m) * 35 + 2 + k]);
  }
  __syncthreads();

  // ---- layer 1 ----
  for (int nt = wv; nt < 13; nt += 4){
    int n = nt * 16 + ln;
    short8 b0 = *(const short8*)(wbf + n * 64 + qd * 8);
    short8 b1 = *(const short8*)(wbf + n * 64 + 32 + qd * 8);
    float bv = (n < 200) ? b1f[n] : 0.f;
    #pragma unroll
    for (int mt = 0; mt < 2; ++mt){
      float4v acc = {bv, bv, bv, bv};
      short8 a0 = *(const short8*)(XB + (mt * 16 + ln) * 72 + qd * 8);
      short8 a1 = *(const short8*)(XB + (mt * 16 + ln) * 72 + 32 + qd * 8);
      acc = __builtin_amdgcn_mfma_f32_16x16x32_bf16(a0, b0, acc, 0, 0, 0);
      acc = __builtin_amdgcn_mfma_f32_16x16x32_bf16(a1, b1, acc, 0, 0, 0);
      #pragma unroll
      for (int r = 0; r < 4; ++r)
        H1[(mt * 16 + qd * 4 + r) * HSTR + n] = (unsigned short)f2bf(lrelu(acc[r]));
    }
  }
  __syncthreads();

  // ---- layer 2 ----
  for (int e = tid; e < 384; e += 256){                             // H2 pad (read in layer 3)
    int m = e / 12, j = e - m * 12;
    ((int*)H2)[m * 117 + 104 + j] = 0;
  }
  {
    const unsigned short* w2p = wbf + W2OFF;
    for (int nt = wv; nt < 13; nt += 4){
      int n = nt * 16 + ln;
      short8 bf[7];
      #pragma unroll
      for (int kc = 0; kc < 7; ++kc)
        bf[kc] = *(const short8*)(w2p + n * 224 + kc * 32 + qd * 8);
      float bv = (n < 200) ? b2f[n] : 0.f;
      #pragma unroll
      for (int mt = 0; mt < 2; ++mt){
        float4v acc = {bv, bv, bv, bv};
        #pragma unroll
        for (int kc = 0; kc < 7; ++kc){
          short8 af = *(const short8*)(H1 + (mt * 16 + ln) * HSTR + kc * 32 + qd * 8);
          acc = __builtin_amdgcn_mfma_f32_16x16x32_bf16(af, bf[kc], acc, 0, 0, 0);
        }
        #pragma unroll
        for (int r = 0; r < 4; ++r)
          H2[(mt * 16 + qd * 4 + r) * HSTR + n] = (unsigned short)f2bf(lrelu(acc[r]));
      }
    }
  }
  __syncthreads();

  // ---- layer 3 (store f16) ----
  {
    const unsigned short* w3p = wbf + W3OFF;
    for (int nt = wv; nt < 7; nt += 4){
      int n = nt * 16 + ln;
      short8 bf[7];
      #pragma unroll
      for (int kc = 0; kc < 7; ++kc)
        bf[kc] = *(const short8*)(w3p + n * 224 + kc * 32 + qd * 8);
      float bv = (n < 100) ? b3f[n] : 0.f;
      #pragma unroll
      for (int mt = 0; mt < 2; ++mt){
        float4v acc = {bv, bv, bv, bv};
        #pragma unroll
        for (int kc = 0; kc < 7; ++kc){
          short8 af = *(const short8*)(H2 + (mt * 16 + ln) * HSTR + kc * 32 + qd * 8);
          acc = __builtin_amdgcn_mfma_f32_16x16x32_bf16(af, bf[kc], acc, 0, 0, 0);
        }
        #pragma unroll
        for (int r = 0; r < 4; ++r)
          H3u[(mt * 16 + qd * 4 + r) * 113 + n] = f2h(acc[r]);
      }
    }
  }
  __syncthreads();

  // paired u32 stores: 2 pixels per store
  for (int e = tid; e < 1600; e += 256){
    int n = e >> 4, mp = e & 15;
    unsigned int lo = H3u[(2 * mp) * 113 + n];
    unsigned int hi = H3u[(2 * mp + 1) * 113 + n];
    *(unsigned int*)(coefb + n * HW + pix0 + 2 * mp) = lo | (hi << 16);
  }
}

// ---------------- K3 v16: banded-Toeplitz MFMA vconv, f16 input, cvt_pk pack ------------
#define VB 344
__global__ __launch_bounds__(256) void k_vconv16(const float* __restrict__ tilt,
    const unsigned short* __restrict__ coefb, const unsigned short* __restrict__ Tt,
    unsigned short* __restrict__ sbuf, unsigned short* __restrict__ smu){
  __shared__ __align__(16) unsigned short sxb[2][16 * VB];
  int tid = threadIdx.x;
  int bid = blockIdx.x;
  int lane = tid & 63, wv = tid >> 6;
  int ln = lane & 15, qd = lane >> 4;
  int col = tid & 15, seg = tid >> 4;
  int r0 = seg * 20;

  int goff[20];
  #pragma unroll
  for (int q = 0; q < 20; ++q) goff[q] = refl(r0 + q - 32) * 256 + col;

  for (int e = tid; e < 768; e += 256){
    int b = e / 384, r = e - b * 384;
    int cc = r / 24, rp = r - cc * 24;
    sxb[b][cc * VB + 320 + rp] = 0;
  }

  if (bid < 640){
    int s = bid & 15;
    int cj = bid >> 4;
    int c = cj / 10, j = cj - c * 10;
    int x0 = s * 16;
    float treg[20];
    if (c < 3){
      const float* tc = tilt + c * HW + x0;
      #pragma unroll
      for (int q = 0; q < 20; ++q) treg[q] = tc[goff[q]];
    }
    unsigned short pf[20];
    {
      const unsigned short* cq = coefb + j * HW + x0;
      #pragma unroll
      for (int q = 0; q < 20; ++q) pf[q] = cq[goff[q]];
    }
    float4v acc[4];
    #pragma unroll
    for (int t = 0; t < 4; ++t) acc[t] = (float4v){0.f, 0.f, 0.f, 0.f};
    for (int i = 0; i < 10; ++i){
      int us = i & 1;
      unsigned short* sb = sxb[us];
      if (c < 3){
        #pragma unroll
        for (int q = 0; q < 10; ++q){
          float v0 = h2f(pf[2 * q]) * treg[2 * q];
          float v1 = h2f(pf[2 * q + 1]) * treg[2 * q + 1];
          *(unsigned int*)&sb[col * VB + r0 + 2 * q] = pk_bf16(v0, v1);
        }
      } else {
        #pragma unroll
        for (int q = 0; q < 10; ++q){
          *(unsigned int*)&sb[col * VB + r0 + 2 * q] = pk_bf16(h2f(pf[2 * q]), h2f(pf[2 * q + 1]));
        }
      }
      __syncthreads();
      if (i < 9){
        const unsigned short* cn = coefb + ((i + 1) * 10 + j) * HW + x0;
        #pragma unroll
        for (int q = 0; q < 20; ++q) pf[q] = cn[goff[q]];
      }
      const unsigned short* ta = Tt + i * 1536 + ln * 96 + qd * 8;
      short8 A0 = *(const short8*)(ta);
      short8 A1 = *(const short8*)(ta + 32);
      short8 A2 = *(const short8*)(ta + 64);
      #pragma unroll
      for (int t = 0; t < 4; ++t){
        int yt = wv * 4 + t;
        const unsigned short* bp = sb + ln * VB + yt * 16 + qd * 8;
        short8 B0 = *(const short8*)(bp);
        short8 B1 = *(const short8*)(bp + 32);
        short8 B2 = *(const short8*)(bp + 64);
        acc[t] = __builtin_amdgcn_mfma_f32_16x16x32_bf16(A0, B0, acc[t], 0, 0, 0);
        acc[t] = __builtin_amdgcn_mfma_f32_16x16x32_bf16(A1, B1, acc[t], 0, 0, 0);
        acc[t] = __builtin_amdgcn_mfma_f32_16x16x32_bf16(A2, B2, acc[t], 0, 0, 0);
      }
    }
    unsigned short* S = sbuf + (c * 10 + j) * HW + x0 + ln;
    #pragma unroll
    for (int t = 0; t < 4; ++t){
      int yt = wv * 4 + t;
      #pragma unroll
      for (int r = 0; r < 4; ++r)
        S[(yt * 16 + qd * 4 + r) * 256] = (unsigned short)f2bf(acc[t][r]);
    }
  } else {
    int b2 = bid - 640;
    int c = b2 >> 4, s = b2 & 15;
    int x0 = s * 16;
    const float* tc = tilt + c * HW + x0;
    float tv[20];
    #pragma unroll
    for (int q = 0; q < 20; ++q) tv[q] = tc[goff[q]];
    #pragma unroll
    for (int q = 0; q < 10; ++q){
      *(unsigned int*)&sxb[0][col * VB + r0 + 2 * q] = pk_bf16(tv[2 * q], tv[2 * q + 1]);
    }
    __syncthreads();
    for (int m = 0; m < 10; ++m){
      const unsigned short* ta = Tt + (10 + m) * 1536 + ln * 96 + qd * 8;
      short8 A0 = *(const short8*)(ta);
      short8 A1 = *(const short8*)(ta + 32);
      short8 A2 = *(const short8*)(ta + 64);
      float4v acc[4];
      #pragma unroll
      for (int t = 0; t < 4; ++t) acc[t] = (float4v){0.f, 0.f, 0.f, 0.f};
      #pragma unroll
      for (int t = 0; t < 4; ++t){
        int yt = wv * 4 + t;
        const unsigned short* bp = sxb[0] + ln * VB + yt * 16 + qd * 8;
        short8 B0 = *(const short8*)(bp);
        short8 B1 = *(const short8*)(bp + 32);
        short8 B2 = *(const short8*)(bp + 64);
        acc[t] = __builtin_amdgcn_mfma_f32_16x16x32_bf16(A0, B0, acc[t], 0, 0, 0);
        acc[t] = __builtin_amdgcn_mfma_f32_16x16x32_bf16(A1, B1, acc[t], 0, 0, 0);
        acc[t] = __builtin_amdgcn_mfma_f32_16x16x32_bf16(A2, B2, acc[t], 0, 0, 0);
      }
      unsigned short* S = smu + (c * 10 + m) * HW + x0 + ln;
      #pragma unroll
      for (int t = 0; t < 4; ++t){
        int yt = wv * 4 + t;
        #pragma unroll
        for (int r = 0; r < 4; ++r)
          S[(yt * 16 + qd * 4 + r) * 256] = (unsigned short)f2bf(acc[t][r]);
      }
    }
  }
}

// ---------------- K4 v9: Toeplitz-MFMA hconv, bf16 INPUT (no f2bf in pack) --------------
#define HS2 344
__global__ __launch_bounds__(256) void k_hconv9(const unsigned short* __restrict__ sbuf,
    const unsigned short* __restrict__ smu, const unsigned short* __restrict__ Tt,
    float* __restrict__ part){
  __shared__ __align__(16) unsigned short sxb[16 * HS2];
  int tid = threadIdx.x;
  int grp = blockIdx.x >> 4;
  int yt  = blockIdx.x & 15;
  int y0 = yt * 16;
  int lane = tid & 63, wv = tid >> 6;
  int ln = lane & 15, qd = lane >> 4;
  int srow = tid >> 4, scol = tid & 15;
  int isbr = (grp < 8);
  int tgt, h;
  if (isbr){ tgt = grp >> 1; h = grp & 1; }
  else     { int g2 = grp - 8; tgt = g2 >> 1; h = g2 & 1; }
  const unsigned short* base = isbr ? (sbuf + tgt * 10 * HW) : (smu + tgt * 10 * HW);
  int tbase = isbr ? 20 : 10;

  for (int e = tid; e < 384; e += 256){
    int rr = e / 24, cp = e - rr * 24;
    sxb[rr * HS2 + 320 + cp] = 0;
  }

  int gx[20];
  #pragma unroll
  for (int q = 0; q < 20; ++q) gx[q] = refl(scol * 20 - 32 + q);

  float4v acc[4];
  #pragma unroll
  for (int t = 0; t < 4; ++t) acc[t] = (float4v){0.f, 0.f, 0.f, 0.f};

  for (int p = 0; p < 5; ++p){
    int col = h * 5 + p;
    const unsigned short* plane = base + col * HW + (y0 + srow) * 256;
    __syncthreads();
    unsigned short v[20];
    #pragma unroll
    for (int q = 0; q < 20; ++q) v[q] = plane[gx[q]];
    #pragma unroll
    for (int q = 0; q < 10; ++q){
      *(unsigned int*)&sxb[srow * HS2 + scol * 20 + 2 * q] =
          (unsigned int)v[2 * q] | ((unsigned int)v[2 * q + 1] << 16);
    }
    __syncthreads();
    const unsigned short* ta = Tt + (tbase + col) * 1536 + ln * 96 + qd * 8;
    short8 A0 = *(const short8*)(ta);
    short8 A1 = *(const short8*)(ta + 32);
    short8 A2 = *(const short8*)(ta + 64);
    #pragma unroll
    for (int t = 0; t < 4; ++t){
      int wt = wv * 4 + t;
      const unsigned short* bp = sxb + ln * HS2 + wt * 16 + qd * 8;
      short8 B0 = *(const short8*)(bp);
      short8 B1 = *(const short8*)(bp + 32);
      short8 B2 = *(const short8*)(bp + 64);
      acc[t] = __builtin_amdgcn_mfma_f32_16x16x32_bf16(A0, B0, acc[t], 0, 0, 0);
      acc[t] = __builtin_amdgcn_mfma_f32_16x16x32_bf16(A1, B1, acc[t], 0, 0, 0);
      acc[t] = __builtin_amdgcn_mfma_f32_16x16x32_bf16(A2, B2, acc[t], 0, 0, 0);
    }
  }
  #pragma unroll
  for (int t = 0; t < 4; ++t){
    int wt = wv * 4 + t;
    float4 res = {acc[t][0], acc[t][1], acc[t][2], acc[t][3]};
    *(float4*)(part + grp * HW + (y0 + ln) * 256 + wt * 16 + qd * 4) = res;
  }
}

// ---------------- K5: out_c = (P2c+P2c+1+P8+2c+P9+2c) / (P6+P7+muC) ---------------------
__global__ __launch_bounds__(256) void k_final(const float* __restrict__ part,
                                               const float* __restrict__ mucp,
                                               float* __restrict__ out){
  int pix = blockIdx.x * 256 + threadIdx.x;
  float muC = mucp[0];
  float den = part[6 * HW + pix] + part[7 * HW + pix] + muC;
  float inv = 1.f / den;
  #pragma unroll
  for (int c = 0; c < 3; ++c){
    float num = part[(2 * c) * HW + pix] + part[(2 * c + 1) * HW + pix]
              + part[(8 + 2 * c) * HW + pix] + part[(9 + 2 * c) * HW + pix];
    out[c * HW + pix] = num * inv;
  }
}

extern "C" void kernel_launch(void* const* d_in, const int* in_sizes, int n_in,
                              void* d_out, int out_size, void* d_ws, size_t ws_size,
                              hipStream_t stream) {
  const float* img  = (const float*)d_in[0];
  const float* zern = (const float*)d_in[1];
  const float* w1   = (const float*)d_in[2];
  const float* b1   = (const float*)d_in[3];
  const float* w2   = (const float*)d_in[4];
  const float* b2   = (const float*)d_in[5];
  const float* w3   = (const float*)d_in[6];
  const float* b3   = (const float*)d_in[7];
  const float* bl   = (const float*)d_in[8];
  const float* br   = (const float*)d_in[9];
  const float* mu   = (const float*)d_in[10];
  float* out = (float*)d_out;

  float* w = (float*)d_ws;
  float* tilt = w;                                        // planes [0,3)
  unsigned short* coefb = (unsigned short*)(w + 3 * HW);  // 100 f16 planes = [3,53); dead after vconv
  float* part = w + 3 * HW;                               // planes [3,17): hconv partials (reuse coefb)
  unsigned short* sbuf = (unsigned short*)(w + 53 * HW);  // 40 bf16 planes [53,73)
  unsigned short* smu  = (unsigned short*)(w + 73 * HW);  // 30 bf16 planes [73,88)
  unsigned short* wbf  = (unsigned short*)(w + 53 * HW);  // bf16 weights, dead before vconv writes sbuf
  unsigned short* Tt   = (unsigned short*)(w + 88 * HW);  // Toeplitz tables, 90 KB
  float* mucp = (float*)(Tt + 46080);                     // 1 float

  k_prep<<<513, 256, 0, stream>>>(w1, w2, w3, bl, br, mu, wbf, Tt, mucp);
  k_mlp<<<2048, 256, 0, stream>>>(img, zern, b1, b2, b3, wbf, tilt, coefb);
  k_vconv16<<<688, 256, 0, stream>>>(tilt, coefb, Tt, sbuf, smu);
  k_hconv9<<<224, 256, 0, stream>>>(sbuf, smu, Tt, part);
  k_final<<<256, 256, 0, stream>>>(part, mucp, out);
}

// Round 5
// 149.238 us; speedup vs baseline: 1.3311x; 1.2986x over previous
//
#include <hip/hip_runtime.h>

#define HW 65536

typedef __attribute__((ext_vector_type(8))) short short8;
typedef __attribute__((ext_vector_type(4))) float float4v;

__device__ __forceinline__ int refl(int i){ if (i < 0) i = -i; if (i > 255) i = 510 - i; return i; }
__device__ __forceinline__ float lrelu(float x){ return x > 0.f ? x : 0.01f * x; }
__device__ __forceinline__ unsigned int f2bf(float x){
  union { float f; unsigned int u; } v; v.f = x;
  unsigned int r = v.u + 0x7fff + ((v.u >> 16) & 1);
  return r >> 16;
}
// HW packed f32->bf16 (RNE) -- bit-identical to f2bf pair, 1 instruction vs ~10.
__device__ __forceinline__ unsigned int pk_bf16(float lo, float hi){
  unsigned int r;
  asm("v_cvt_pk_bf16_f32 %0, %1, %2" : "=v"(r) : "v"(lo), "v"(hi));
  return r;
}
__device__ __forceinline__ unsigned short f2h(float x){
  union { _Float16 h; unsigned short u; } v; v.h = (_Float16)x; return v.u;
}
__device__ __forceinline__ float h2f(unsigned short u){
  union { _Float16 h; unsigned short u; } v; v.u = u; return (float)v.h;
}

// ---------------- K_prep: weight convert + Toeplitz tables (blocks 0..511), muC (512) ---
#define W2OFF 13312
#define W3OFF 59904
__global__ __launch_bounds__(256) void k_prep(const float* __restrict__ w1,
    const float* __restrict__ w2, const float* __restrict__ w3,
    const float* __restrict__ bl, const float* __restrict__ br,
    const float* __restrict__ mu, unsigned short* __restrict__ wbf,
    unsigned short* __restrict__ Tt, float* __restrict__ mucp){
  __shared__ float sm[650];
  __shared__ float sq[10];
  int bid = blockIdx.x;
  int tid = threadIdx.x;
  if (bid < 512){
    int i = bid * 256 + tid;
    if (i < 84992){
      if (i < 208 * 64){
        int n = i >> 6, k = i & 63;
        float v = (n < 200 && k < 33) ? w1[n * 33 + k] : 0.f;
        wbf[i] = (unsigned short)f2bf(v);
      } else if (i < W2OFF + 208 * 224){
        int j = i - W2OFF; int n = j / 224, k = j - n * 224;
        float v = (n < 200 && k < 200) ? w2[n * 200 + k] : 0.f;
        wbf[i] = (unsigned short)f2bf(v);
      } else {
        int j = i - W3OFF; int n = j / 224, k = j - n * 224;
        float v = (n < 100 && k < 200) ? w3[n * 200 + k] : 0.f;
        wbf[i] = (unsigned short)f2bf(v);
      }
    } else {
      int e = i - 84992;                 // < 46080
      int t = e / 1536, rem = e - t * 1536;
      int m = rem / 96, k = rem - m * 96;
      int d = k - m;
      float v = 0.f;
      if (d >= 0 && d <= 64){
        if (t < 10)      v = bl[d * 10 + t];
        else if (t < 20) v = mu[d * 10 + (t - 10)];
        else             v = br[d * 10 + (t - 20)];
      }
      Tt[e] = (unsigned short)f2bf(v);
    }
  } else {
    // ---- muC = sum_m (sum_u mu[u,m])^2, same op order as reference k_final ----
    for (int e = tid; e < 650; e += 256) sm[e] = mu[e];
    __syncthreads();
    if (tid < 10){
      float s = 0.f;
      for (int u = 0; u < 65; ++u) s += sm[u * 10 + tid];
      sq[tid] = s * s;
    }
    __syncthreads();
    if (tid == 0){
      float m = 0.f;
      #pragma unroll
      for (int mm = 0; mm < 10; ++mm) m += sq[mm];
      mucp[0] = m;
    }
  }
}

// ---------------- Fused MLP + gridsample: 32-pixel tile, 512 threads (8 waves) ----------
// HSTR=232 (29 x 8 shorts): rows 16B-aligned for ds_read_b128 -- HSTR=234 (R3/R4) broke
// alignment and DOUBLED the kernel (81.7us). 232 is also b128 bank-optimal (8/bank).
// 8 waves: nt-loop serial depth 4/4/2 -> 2/2/1; 4 blocks x 512 thr = 2048/CU (max TLP).
#define HSTR 232
#define BUFB 14848
__global__ __launch_bounds__(512) void k_mlp(const float* __restrict__ img,
    const float* __restrict__ zern,
    const float* __restrict__ b1f, const float* __restrict__ b2f,
    const float* __restrict__ b3f, const unsigned short* __restrict__ wbf,
    float* __restrict__ tilt, unsigned short* __restrict__ coefb){
  __shared__ char smem[2 * BUFB];
  unsigned short* H1  = (unsigned short*)smem;            // 32 x HSTR
  unsigned short* H3u = (unsigned short*)smem;            // 32 x 113 f16 (alias H1)
  unsigned short* XB  = (unsigned short*)(smem + BUFB);   // 32 x 72
  unsigned short* H2  = XB;                               // 32 x HSTR (alias XB)
  int tid = threadIdx.x;
  int pix0 = blockIdx.x * 32;
  int lane = tid & 63, wv = tid >> 6;                     // wv in [0,8)
  int ln = lane & 15, qd = lane >> 4;

  // ---- bilinear grid sample (border, align_corners=False) for this tile ----
  if (tid < 96){
    int m = tid & 31, c = tid >> 5;
    int pix = pix0 + m;
    int x = pix & 255, y = pix >> 8;
    float px = zern[pix * 35 + 0], py = zern[pix * 35 + 1];
    float ix = ((float)x + px) * (256.f / 255.f) - 0.5f;
    float iy = ((float)y + py) * (256.f / 255.f) - 0.5f;
    ix = fminf(fmaxf(ix, 0.f), 255.f);
    iy = fminf(fmaxf(iy, 0.f), 255.f);
    float x0f = floorf(ix), y0f = floorf(iy);
    float wx = ix - x0f, wy = iy - y0f;
    int x0 = (int)x0f, y0 = (int)y0f;
    int x1 = min(x0 + 1, 255), y1 = min(y0 + 1, 255);
    const float* im = img + c * HW;
    float g00 = im[y0 * 256 + x0], g01 = im[y0 * 256 + x1];
    float g10 = im[y1 * 256 + x0], g11 = im[y1 * 256 + x1];
    float top = g00 * (1.f - wx) + g01 * wx;
    float bot = g10 * (1.f - wx) + g11 * wx;
    tilt[c * HW + pix] = top * (1.f - wy) + bot * wy;
  }

  for (int e = tid; e < 1152; e += 512) ((int*)XB)[e] = 0;          // whole XB
  for (int e = tid; e < 384; e += 512){                             // H1 pad shorts 208..231
    int m = e / 12, j = e - m * 12;
    ((int*)H1)[m * 116 + 104 + j] = 0;
  }
  __syncthreads();
  for (int e = tid; e < 32 * 33; e += 512){
    int m = e / 33, k = e - m * 33;
    XB[m * 72 + k] = (unsigned short)f2bf(zern[(pix0 + m) * 35 + 2 + k]);
  }
  __syncthreads();

  // ---- layer 1 ----
  for (int nt = wv; nt < 13; nt += 8){
    int n = nt * 16 + ln;
    short8 b0 = *(const short8*)(wbf + n * 64 + qd * 8);
    short8 b1 = *(const short8*)(wbf + n * 64 + 32 + qd * 8);
    float bv = (n < 200) ? b1f[n] : 0.f;
    #pragma unroll
    for (int mt = 0; mt < 2; ++mt){
      float4v acc = {bv, bv, bv, bv};
      short8 a0 = *(const short8*)(XB + (mt * 16 + ln) * 72 + qd * 8);
      short8 a1 = *(const short8*)(XB + (mt * 16 + ln) * 72 + 32 + qd * 8);
      acc = __builtin_amdgcn_mfma_f32_16x16x32_bf16(a0, b0, acc, 0, 0, 0);
      acc = __builtin_amdgcn_mfma_f32_16x16x32_bf16(a1, b1, acc, 0, 0, 0);
      #pragma unroll
      for (int r = 0; r < 4; ++r)
        H1[(mt * 16 + qd * 4 + r) * HSTR + n] = (unsigned short)f2bf(lrelu(acc[r]));
    }
  }
  __syncthreads();

  // ---- layer 2 ----
  for (int e = tid; e < 384; e += 512){                             // H2 pad (read in layer 3)
    int m = e / 12, j = e - m * 12;
    ((int*)H2)[m * 116 + 104 + j] = 0;
  }
  {
    const unsigned short* w2p = wbf + W2OFF;
    for (int nt = wv; nt < 13; nt += 8){
      int n = nt * 16 + ln;
      short8 bf[7];
      #pragma unroll
      for (int kc = 0; kc < 7; ++kc)
        bf[kc] = *(const short8*)(w2p + n * 224 + kc * 32 + qd * 8);
      float bv = (n < 200) ? b2f[n] : 0.f;
      #pragma unroll
      for (int mt = 0; mt < 2; ++mt){
        float4v acc = {bv, bv, bv, bv};
        #pragma unroll
        for (int kc = 0; kc < 7; ++kc){
          short8 af = *(const short8*)(H1 + (mt * 16 + ln) * HSTR + kc * 32 + qd * 8);
          acc = __builtin_amdgcn_mfma_f32_16x16x32_bf16(af, bf[kc], acc, 0, 0, 0);
        }
        #pragma unroll
        for (int r = 0; r < 4; ++r)
          H2[(mt * 16 + qd * 4 + r) * HSTR + n] = (unsigned short)f2bf(lrelu(acc[r]));
      }
    }
  }
  __syncthreads();

  // ---- layer 3 (store f16) ----
  {
    const unsigned short* w3p = wbf + W3OFF;
    for (int nt = wv; nt < 7; nt += 8){
      int n = nt * 16 + ln;
      short8 bf[7];
      #pragma unroll
      for (int kc = 0; kc < 7; ++kc)
        bf[kc] = *(const short8*)(w3p + n * 224 + kc * 32 + qd * 8);
      float bv = (n < 100) ? b3f[n] : 0.f;
      #pragma unroll
      for (int mt = 0; mt < 2; ++mt){
        float4v acc = {bv, bv, bv, bv};
        #pragma unroll
        for (int kc = 0; kc < 7; ++kc){
          short8 af = *(const short8*)(H2 + (mt * 16 + ln) * HSTR + kc * 32 + qd * 8);
          acc = __builtin_amdgcn_mfma_f32_16x16x32_bf16(af, bf[kc], acc, 0, 0, 0);
        }
        #pragma unroll
        for (int r = 0; r < 4; ++r)
          H3u[(mt * 16 + qd * 4 + r) * 113 + n] = f2h(acc[r]);
      }
    }
  }
  __syncthreads();

  // paired u32 stores: 2 pixels per store
  for (int e = tid; e < 1600; e += 512){
    int n = e >> 4, mp = e & 15;
    unsigned int lo = H3u[(2 * mp) * 113 + n];
    unsigned int hi = H3u[(2 * mp + 1) * 113 + n];
    *(unsigned int*)(coefb + n * HW + pix0 + 2 * mp) = lo | (hi << 16);
  }
}

// ---------------- K3 v16: banded-Toeplitz MFMA vconv, f16 input, cvt_pk pack ------------
#define VB 344
__global__ __launch_bounds__(256) void k_vconv16(const float* __restrict__ tilt,
    const unsigned short* __restrict__ coefb, const unsigned short* __restrict__ Tt,
    unsigned short* __restrict__ sbuf, unsigned short* __restrict__ smu){
  __shared__ __align__(16) unsigned short sxb[2][16 * VB];
  int tid = threadIdx.x;
  int bid = blockIdx.x;
  int lane = tid & 63, wv = tid >> 6;
  int ln = lane & 15, qd = lane >> 4;
  int col = tid & 15, seg = tid >> 4;
  int r0 = seg * 20;

  int goff[20];
  #pragma unroll
  for (int q = 0; q < 20; ++q) goff[q] = refl(r0 + q - 32) * 256 + col;

  for (int e = tid; e < 768; e += 256){
    int b = e / 384, r = e - b * 384;
    int cc = r / 24, rp = r - cc * 24;
    sxb[b][cc * VB + 320 + rp] = 0;
  }

  if (bid < 640){
    int s = bid & 15;
    int cj = bid >> 4;
    int c = cj / 10, j = cj - c * 10;
    int x0 = s * 16;
    float treg[20];
    if (c < 3){
      const float* tc = tilt + c * HW + x0;
      #pragma unroll
      for (int q = 0; q < 20; ++q) treg[q] = tc[goff[q]];
    }
    unsigned short pf[20];
    {
      const unsigned short* cq = coefb + j * HW + x0;
      #pragma unroll
      for (int q = 0; q < 20; ++q) pf[q] = cq[goff[q]];
    }
    float4v acc[4];
    #pragma unroll
    for (int t = 0; t < 4; ++t) acc[t] = (float4v){0.f, 0.f, 0.f, 0.f};
    for (int i = 0; i < 10; ++i){
      int us = i & 1;
      unsigned short* sb = sxb[us];
      if (c < 3){
        #pragma unroll
        for (int q = 0; q < 10; ++q){
          float v0 = h2f(pf[2 * q]) * treg[2 * q];
          float v1 = h2f(pf[2 * q + 1]) * treg[2 * q + 1];
          *(unsigned int*)&sb[col * VB + r0 + 2 * q] = pk_bf16(v0, v1);
        }
      } else {
        #pragma unroll
        for (int q = 0; q < 10; ++q){
          *(unsigned int*)&sb[col * VB + r0 + 2 * q] = pk_bf16(h2f(pf[2 * q]), h2f(pf[2 * q + 1]));
        }
      }
      __syncthreads();
      if (i < 9){
        const unsigned short* cn = coefb + ((i + 1) * 10 + j) * HW + x0;
        #pragma unroll
        for (int q = 0; q < 20; ++q) pf[q] = cn[goff[q]];
      }
      const unsigned short* ta = Tt + i * 1536 + ln * 96 + qd * 8;
      short8 A0 = *(const short8*)(ta);
      short8 A1 = *(const short8*)(ta + 32);
      short8 A2 = *(const short8*)(ta + 64);
      #pragma unroll
      for (int t = 0; t < 4; ++t){
        int yt = wv * 4 + t;
        const unsigned short* bp = sb + ln * VB + yt * 16 + qd * 8;
        short8 B0 = *(const short8*)(bp);
        short8 B1 = *(const short8*)(bp + 32);
        short8 B2 = *(const short8*)(bp + 64);
        acc[t] = __builtin_amdgcn_mfma_f32_16x16x32_bf16(A0, B0, acc[t], 0, 0, 0);
        acc[t] = __builtin_amdgcn_mfma_f32_16x16x32_bf16(A1, B1, acc[t], 0, 0, 0);
        acc[t] = __builtin_amdgcn_mfma_f32_16x16x32_bf16(A2, B2, acc[t], 0, 0, 0);
      }
    }
    unsigned short* S = sbuf + (c * 10 + j) * HW + x0 + ln;
    #pragma unroll
    for (int t = 0; t < 4; ++t){
      int yt = wv * 4 + t;
      #pragma unroll
      for (int r = 0; r < 4; ++r)
        S[(yt * 16 + qd * 4 + r) * 256] = (unsigned short)f2bf(acc[t][r]);
    }
  } else {
    int b2 = bid - 640;
    int c = b2 >> 4, s = b2 & 15;
    int x0 = s * 16;
    const float* tc = tilt + c * HW + x0;
    float tv[20];
    #pragma unroll
    for (int q = 0; q < 20; ++q) tv[q] = tc[goff[q]];
    #pragma unroll
    for (int q = 0; q < 10; ++q){
      *(unsigned int*)&sxb[0][col * VB + r0 + 2 * q] = pk_bf16(tv[2 * q], tv[2 * q + 1]);
    }
    __syncthreads();
    for (int m = 0; m < 10; ++m){
      const unsigned short* ta = Tt + (10 + m) * 1536 + ln * 96 + qd * 8;
      short8 A0 = *(const short8*)(ta);
      short8 A1 = *(const short8*)(ta + 32);
      short8 A2 = *(const short8*)(ta + 64);
      float4v acc[4];
      #pragma unroll
      for (int t = 0; t < 4; ++t) acc[t] = (float4v){0.f, 0.f, 0.f, 0.f};
      #pragma unroll
      for (int t = 0; t < 4; ++t){
        int yt = wv * 4 + t;
        const unsigned short* bp = sxb[0] + ln * VB + yt * 16 + qd * 8;
        short8 B0 = *(const short8*)(bp);
        short8 B1 = *(const short8*)(bp + 32);
        short8 B2 = *(const short8*)(bp + 64);
        acc[t] = __builtin_amdgcn_mfma_f32_16x16x32_bf16(A0, B0, acc[t], 0, 0, 0);
        acc[t] = __builtin_amdgcn_mfma_f32_16x16x32_bf16(A1, B1, acc[t], 0, 0, 0);
        acc[t] = __builtin_amdgcn_mfma_f32_16x16x32_bf16(A2, B2, acc[t], 0, 0, 0);
      }
      unsigned short* S = smu + (c * 10 + m) * HW + x0 + ln;
      #pragma unroll
      for (int t = 0; t < 4; ++t){
        int yt = wv * 4 + t;
        #pragma unroll
        for (int r = 0; r < 4; ++r)
          S[(yt * 16 + qd * 4 + r) * 256] = (unsigned short)f2bf(acc[t][r]);
      }
    }
  }
}

// ---------------- K4 v9: Toeplitz-MFMA hconv, bf16 INPUT (no f2bf in pack) --------------
#define HS2 344
__global__ __launch_bounds__(256) void k_hconv9(const unsigned short* __restrict__ sbuf,
    const unsigned short* __restrict__ smu, const unsigned short* __restrict__ Tt,
    float* __restrict__ part){
  __shared__ __align__(16) unsigned short sxb[16 * HS2];
  int tid = threadIdx.x;
  int grp = blockIdx.x >> 4;
  int yt  = blockIdx.x & 15;
  int y0 = yt * 16;
  int lane = tid & 63, wv = tid >> 6;
  int ln = lane & 15, qd = lane >> 4;
  int srow = tid >> 4, scol = tid & 15;
  int isbr = (grp < 8);
  int tgt, h;
  if (isbr){ tgt = grp >> 1; h = grp & 1; }
  else     { int g2 = grp - 8; tgt = g2 >> 1; h = g2 & 1; }
  const unsigned short* base = isbr ? (sbuf + tgt * 10 * HW) : (smu + tgt * 10 * HW);
  int tbase = isbr ? 20 : 10;

  for (int e = tid; e < 384; e += 256){
    int rr = e / 24, cp = e - rr * 24;
    sxb[rr * HS2 + 320 + cp] = 0;
  }

  int gx[20];
  #pragma unroll
  for (int q = 0; q < 20; ++q) gx[q] = refl(scol * 20 - 32 + q);

  float4v acc[4];
  #pragma unroll
  for (int t = 0; t < 4; ++t) acc[t] = (float4v){0.f, 0.f, 0.f, 0.f};

  for (int p = 0; p < 5; ++p){
    int col = h * 5 + p;
    const unsigned short* plane = base + col * HW + (y0 + srow) * 256;
    __syncthreads();
    unsigned short v[20];
    #pragma unroll
    for (int q = 0; q < 20; ++q) v[q] = plane[gx[q]];
    #pragma unroll
    for (int q = 0; q < 10; ++q){
      *(unsigned int*)&sxb[srow * HS2 + scol * 20 + 2 * q] =
          (unsigned int)v[2 * q] | ((unsigned int)v[2 * q + 1] << 16);
    }
    __syncthreads();
    const unsigned short* ta = Tt + (tbase + col) * 1536 + ln * 96 + qd * 8;
    short8 A0 = *(const short8*)(ta);
    short8 A1 = *(const short8*)(ta + 32);
    short8 A2 = *(const short8*)(ta + 64);
    #pragma unroll
    for (int t = 0; t < 4; ++t){
      int wt = wv * 4 + t;
      const unsigned short* bp = sxb + ln * HS2 + wt * 16 + qd * 8;
      short8 B0 = *(const short8*)(bp);
      short8 B1 = *(const short8*)(bp + 32);
      short8 B2 = *(const short8*)(bp + 64);
      acc[t] = __builtin_amdgcn_mfma_f32_16x16x32_bf16(A0, B0, acc[t], 0, 0, 0);
      acc[t] = __builtin_amdgcn_mfma_f32_16x16x32_bf16(A1, B1, acc[t], 0, 0, 0);
      acc[t] = __builtin_amdgcn_mfma_f32_16x16x32_bf16(A2, B2, acc[t], 0, 0, 0);
    }
  }
  #pragma unroll
  for (int t = 0; t < 4; ++t){
    int wt = wv * 4 + t;
    float4 res = {acc[t][0], acc[t][1], acc[t][2], acc[t][3]};
    *(float4*)(part + grp * HW + (y0 + ln) * 256 + wt * 16 + qd * 4) = res;
  }
}

// ---------------- K5: out_c = (P2c+P2c+1+P8+2c+P9+2c) / (P6+P7+muC) ---------------------
__global__ __launch_bounds__(256) void k_final(const float* __restrict__ part,
                                               const float* __restrict__ mucp,
                                               float* __restrict__ out){
  int pix = blockIdx.x * 256 + threadIdx.x;
  float muC = mucp[0];
  float den = part[6 * HW + pix] + part[7 * HW + pix] + muC;
  float inv = 1.f / den;
  #pragma unroll
  for (int c = 0; c < 3; ++c){
    float num = part[(2 * c) * HW + pix] + part[(2 * c + 1) * HW + pix]
              + part[(8 + 2 * c) * HW + pix] + part[(9 + 2 * c) * HW + pix];
    out[c * HW + pix] = num * inv;
  }
}

extern "C" void kernel_launch(void* const* d_in, const int* in_sizes, int n_in,
                              void* d_out, int out_size, void* d_ws, size_t ws_size,
                              hipStream_t stream) {
  const float* img  = (const float*)d_in[0];
  const float* zern = (const float*)d_in[1];
  const float* w1   = (const float*)d_in[2];
  const float* b1   = (const float*)d_in[3];
  const float* w2   = (const float*)d_in[4];
  const float* b2   = (const float*)d_in[5];
  const float* w3   = (const float*)d_in[6];
  const float* b3   = (const float*)d_in[7];
  const float* bl   = (const float*)d_in[8];
  const float* br   = (const float*)d_in[9];
  const float* mu   = (const float*)d_in[10];
  float* out = (float*)d_out;

  float* w = (float*)d_ws;
  float* tilt = w;                                        // planes [0,3)
  unsigned short* coefb = (unsigned short*)(w + 3 * HW);  // 100 f16 planes = [3,53); dead after vconv
  float* part = w + 3 * HW;                               // planes [3,17): hconv partials (reuse coefb)
  unsigned short* sbuf = (unsigned short*)(w + 53 * HW);  // 40 bf16 planes [53,73)
  unsigned short* smu  = (unsigned short*)(w + 73 * HW);  // 30 bf16 planes [73,88)
  unsigned short* wbf  = (unsigned short*)(w + 53 * HW);  // bf16 weights, dead before vconv writes sbuf
  unsigned short* Tt   = (unsigned short*)(w + 88 * HW);  // Toeplitz tables, 90 KB
  float* mucp = (float*)(Tt + 46080);                     // 1 float

  k_prep<<<513, 256, 0, stream>>>(w1, w2, w3, bl, br, mu, wbf, Tt, mucp);
  k_mlp<<<2048, 512, 0, stream>>>(img, zern, b1, b2, b3, wbf, tilt, coefb);
  k_vconv16<<<688, 256, 0, stream>>>(tilt, coefb, Tt, sbuf, smu);
  k_hconv9<<<224, 256, 0, stream>>>(sbuf, smu, Tt, part);
  k_final<<<256, 256, 0, stream>>>(part, mucp, out);
}